// Round 3
// baseline (1719.852 us; speedup 1.0000x reference)
//
#include <hip/hip_runtime.h>
#include <hip/hip_fp16.h>

typedef __attribute__((ext_vector_type(8))) short  s16x8;   // 8x16-bit (4 VGPRs)
typedef __attribute__((ext_vector_type(4))) float  f32x4;   // MFMA C/D frag
typedef __attribute__((ext_vector_type(4))) unsigned short u16x4;
typedef _Float16 f16x2 __attribute__((ext_vector_type(2)));
typedef _Float16 f16x8 __attribute__((ext_vector_type(8)));
typedef unsigned short u16;

#define MFMA16B(A, B, C) __builtin_amdgcn_mfma_f32_16x16x32_bf16((A), (B), (C), 0, 0, 0)
#define MFMA16H(A, B, C) __builtin_amdgcn_mfma_f32_16x16x32_f16((A), (B), (C), 0, 0, 0)

static __device__ __forceinline__ u16 f2bf(float f) {
    union { float f; unsigned u; } v; v.f = f;
    unsigned r = (v.u + 0x7fffu + ((v.u >> 16) & 1u)) >> 16;   // RNE
    return (u16)r;
}

static __device__ __forceinline__ s16x8 pack_f16x8(float4 a, float4 b) {
    s16x8 r;
    r[0] = (short)__half_as_ushort(__float2half_rn(a.x));
    r[1] = (short)__half_as_ushort(__float2half_rn(a.y));
    r[2] = (short)__half_as_ushort(__float2half_rn(a.z));
    r[3] = (short)__half_as_ushort(__float2half_rn(a.w));
    r[4] = (short)__half_as_ushort(__float2half_rn(b.x));
    r[5] = (short)__half_as_ushort(__float2half_rn(b.y));
    r[6] = (short)__half_as_ushort(__float2half_rn(b.z));
    r[7] = (short)__half_as_ushort(__float2half_rn(b.w));
    return r;
}

static __device__ __forceinline__ unsigned pk2f16(float a, float b) {
    unsigned lo = __half_as_ushort(__float2half_rn(a));
    unsigned hi = __half_as_ushort(__float2half_rn(b));
    return lo | (hi << 16);
}

static __device__ __forceinline__ float hu2f(u16 v) {
    __half_raw hr; hr.x = v; return __half2float(__half(hr));
}

// 2-way f16 dot with f32 accumulate: v_dot2_f32_f16.
static __device__ __forceinline__ float dot2(unsigned a, unsigned b, float c) {
#if __has_builtin(__builtin_amdgcn_fdot2)
    return __builtin_amdgcn_fdot2(__builtin_bit_cast(f16x2, a),
                                  __builtin_bit_cast(f16x2, b), c, false);
#else
    f16x2 av = __builtin_bit_cast(f16x2, a), bv = __builtin_bit_cast(f16x2, b);
    return fmaf((float)av[0], (float)bv[0], fmaf((float)av[1], (float)bv[1], c));
#endif
}

// fast sigmoid / tanh via v_exp + v_rcp (saturating, NaN-free at extremes)
static __device__ __forceinline__ float sigm(float x) {
    return __builtin_amdgcn_rcpf(1.f + __expf(-x));
}
static __device__ __forceinline__ float tanh_f(float x) {
    float e = __expf(-2.f * x);          // x->-inf: e=inf -> rcp=0 -> -1; x->+inf: e=0 -> +1
    return fmaf(2.f, __builtin_amdgcn_rcpf(1.f + e), -1.f);
}

// LDS-only workgroup barrier (no vmcnt drain -> global prefetch stays in flight).
static __device__ __forceinline__ void wg_barrier() {
    asm volatile("s_waitcnt lgkmcnt(0)\n\ts_barrier" ::: "memory");
}

// ---------------------------------------------------------------------------
// K1: x_gates[m=131072][512] (fp16) = x[m][300] @ W_ih^T + (b_ih + b_hh)
// v6: output columns GATE-INTERLEAVED: column n' = col*4 + gate, i.e.
// xg[m][col][4] holds {i,f,g,o} preacts of h-column `col` contiguously, so K2
// threads read their 4 gates as one 8-B load. Implemented purely as a B-row
// permutation at staging time (stores stay fully coalesced):
//   Bs row srow <- W_ih row grow(srow) = (srow&3)*128 + (n0>>2) + (srow>>2).
// grid (4, 1024): 4 n-blocks sharing an x-tile are dispatch-adjacent (L2 reuse).
// ---------------------------------------------------------------------------
__global__ __launch_bounds__(256, 2)
void k1_gemm_xgates(const float* __restrict__ x, const float* __restrict__ W_ih,
                    const float* __restrict__ b_ih, const float* __restrict__ b_hh,
                    __half* __restrict__ xg) {
    const int n0 = blockIdx.x * 128;       // 4 blocks
    const int m0 = blockIdx.y * 128;       // 1024 blocks
    const int tid = threadIdx.x;
    const int wave = tid >> 6, lane = tid & 63;
    const int lanelo = lane & 15, quad = lane >> 4;
    const int mw = (wave & 1) * 64, nw = (wave >> 1) * 64;

    __shared__ __align__(16) u16 As[128 * 40];
    __shared__ __align__(16) u16 Bs[128 * 40];

    f32x4 acc[4][4];
#pragma unroll
    for (int i = 0; i < 4; ++i)
#pragma unroll
        for (int j = 0; j < 4; ++j) acc[i][j] = (f32x4)0.f;

    const int srow = tid >> 1;
    const int scol = (tid & 1) * 16;
    // permuted gate-row for this staging row (n' = n0+srow -> W row)
    const int grow = (srow & 3) * 128 + (n0 >> 2) + (srow >> 2);

    for (int kc = 0; kc < 10; ++kc) {
        const int k0 = kc * 32;
        const float* srcA = x + (size_t)(m0 + srow) * 300 + k0 + scol;
        const float* srcB = W_ih + (size_t)grow * 300 + k0 + scol;
        if (kc < 9) {                       // full chunk, no bounds checks
#pragma unroll
            for (int i = 0; i < 4; ++i) {
                const int col = scol + i * 4;
                float4 v = *(const float4*)(srcA + i * 4);
                u16x4 w; w.x = f2bf(v.x); w.y = f2bf(v.y); w.z = f2bf(v.z); w.w = f2bf(v.w);
                *(u16x4*)&As[srow * 40 + col] = w;
                float4 u = *(const float4*)(srcB + i * 4);
                u16x4 q; q.x = f2bf(u.x); q.y = f2bf(u.y); q.z = f2bf(u.z); q.w = f2bf(u.w);
                *(u16x4*)&Bs[srow * 40 + col] = q;
            }
        } else {                            // tail chunk (K 288..299, rest zero)
#pragma unroll
            for (int i = 0; i < 4; ++i) {
                const int col = scol + i * 4;
                float4 v = {0.f, 0.f, 0.f, 0.f}, u = {0.f, 0.f, 0.f, 0.f};
                if (k0 + col + 3 < 300) { v = *(const float4*)(srcA + i * 4);
                                          u = *(const float4*)(srcB + i * 4); }
                u16x4 w; w.x = f2bf(v.x); w.y = f2bf(v.y); w.z = f2bf(v.z); w.w = f2bf(v.w);
                *(u16x4*)&As[srow * 40 + col] = w;
                u16x4 q; q.x = f2bf(u.x); q.y = f2bf(u.y); q.z = f2bf(u.z); q.w = f2bf(u.w);
                *(u16x4*)&Bs[srow * 40 + col] = q;
            }
        }
        __syncthreads();

        s16x8 af[4], bf[4];
#pragma unroll
        for (int mt = 0; mt < 4; ++mt)
            af[mt] = *(const s16x8*)&As[(mw + mt * 16 + lanelo) * 40 + quad * 8];
#pragma unroll
        for (int nt = 0; nt < 4; ++nt)
            bf[nt] = *(const s16x8*)&Bs[(nw + nt * 16 + lanelo) * 40 + quad * 8];
#pragma unroll
        for (int mt = 0; mt < 4; ++mt)
#pragma unroll
            for (int nt = 0; nt < 4; ++nt)
                acc[mt][nt] = MFMA16B(af[mt], bf[nt], acc[mt][nt]);
        __syncthreads();
    }

#pragma unroll
    for (int nt = 0; nt < 4; ++nt) {
        const int n = n0 + nw + nt * 16 + lanelo;      // permuted output column
        const int g = (n & 3) * 128 + (n >> 2);        // original gate row
        const float bs = b_ih[g] + b_hh[g];
#pragma unroll
        for (int mt = 0; mt < 4; ++mt) {
            const int mr = m0 + mw + mt * 16 + quad * 4;
#pragma unroll
            for (int r = 0; r < 4; ++r)
                xg[(size_t)(mr + r) * 512 + n] = __float2half(acc[mt][nt][r] + bs);
        }
    }
}

// ---------------------------------------------------------------------------
// K2 v6: LSTM recurrence, all 4 gates per thread -> zero exchange.
//   128 WGs (one batch row) x 128 threads (2 waves). Thread hj owns h-column
//   hj: W_hh rows {hj, 128+hj, 256+hj, 384+hj} stationary as packed-f16 pairs
//   (256 VGPRs). Cell update fully in-thread: no shfl, no divergence.
//   h ping-pong in LDS (2x256B) -> ONE 2-wave barrier per step.
//   xg (gate-interleaved by K1) read as one 8-B global load per thread per
//   step, register-prefetched 2 steps ahead; never drained at barriers.
//   Per-step: 16 b128 h-broadcast reads + 256 dot2 (8 acc chains) + ~30 VALU
//   cell + 1 barrier  ->  ~750 cy/step predicted.
// ---------------------------------------------------------------------------
__global__ __launch_bounds__(128, 1)
void k2_lstm_rec(const __half* __restrict__ xg_all, const float* __restrict__ W_hh,
                 __half* __restrict__ h_seq) {
    const int b = blockIdx.x;             // batch row 0..127
    const int hj = threadIdx.x;           // h column 0..127

    __shared__ __align__(16) unsigned hbuf[2][64];    // ping-pong h (f16 packed)

    // --- stationary W_hh gate rows (f32 -> packed f16 pairs in VGPRs)
    unsigned wI[64], wF[64], wG[64], wO[64];
    {
        const float2* rI = (const float2*)(W_hh + (size_t)(  0 + hj) * 128);
        const float2* rF = (const float2*)(W_hh + (size_t)(128 + hj) * 128);
        const float2* rG = (const float2*)(W_hh + (size_t)(256 + hj) * 128);
        const float2* rO = (const float2*)(W_hh + (size_t)(384 + hj) * 128);
#pragma unroll
        for (int k = 0; k < 64; ++k) {
            float2 a = rI[k]; wI[k] = pk2f16(a.x, a.y);
            float2 f = rF[k]; wF[k] = pk2f16(f.x, f.y);
            float2 g = rG[k]; wG[k] = pk2f16(g.x, g.y);
            float2 o = rO[k]; wO[k] = pk2f16(o.x, o.y);
        }
    }

    if (hj < 64) { hbuf[0][hj] = 0u; }    // h(-1) = 0

    // xg: [t][col][4] u16 -> uint2 element index t*128 + hj
    const uint2* xp = (const uint2*)(xg_all + (size_t)b * 1024 * 512);
    uint2 xa = xp[0 * 128 + hj];          // t=0 preacts (i,f,g,o)
    uint2 xb = xp[1 * 128 + hj];          // t=1
    float c = 0.f;
    __half* hout = h_seq + (size_t)b * 1024 * 128 + hj;
    __syncthreads();

#define STEP(T, RB, WB, XR, NXT) do {                                           \
        const uint4* _hp = (const uint4*)&hbuf[RB][0];                          \
        float ai0 = 0.f, ai1 = 0.f, af0 = 0.f, af1 = 0.f;                       \
        float ag0 = 0.f, ag1 = 0.f, ao0 = 0.f, ao1 = 0.f;                       \
        _Pragma("unroll")                                                       \
        for (int _j = 0; _j < 16; ++_j) {                                       \
            const uint4 _hv = _hp[_j];                                          \
            const int _k = _j * 4;                                              \
            ai0 = dot2(wI[_k + 0], _hv.x, ai0); ai1 = dot2(wI[_k + 1], _hv.y, ai1); \
            ai0 = dot2(wI[_k + 2], _hv.z, ai0); ai1 = dot2(wI[_k + 3], _hv.w, ai1); \
            af0 = dot2(wF[_k + 0], _hv.x, af0); af1 = dot2(wF[_k + 1], _hv.y, af1); \
            af0 = dot2(wF[_k + 2], _hv.z, af0); af1 = dot2(wF[_k + 3], _hv.w, af1); \
            ag0 = dot2(wG[_k + 0], _hv.x, ag0); ag1 = dot2(wG[_k + 1], _hv.y, ag1); \
            ag0 = dot2(wG[_k + 2], _hv.z, ag0); ag1 = dot2(wG[_k + 3], _hv.w, ag1); \
            ao0 = dot2(wO[_k + 0], _hv.x, ao0); ao1 = dot2(wO[_k + 1], _hv.y, ao1); \
            ao0 = dot2(wO[_k + 2], _hv.z, ao0); ao1 = dot2(wO[_k + 3], _hv.w, ao1); \
        }                                                                       \
        const float xi = hu2f((u16)(XR.x & 0xffffu));                           \
        const float xf = hu2f((u16)(XR.x >> 16));                               \
        const float xgp = hu2f((u16)(XR.y & 0xffffu));                          \
        const float xo = hu2f((u16)(XR.y >> 16));                               \
        XR = xp[(size_t)(NXT) * 128 + hj];       /* prefetch 2 ahead */         \
        const float ig = sigm(ai0 + ai1 + xi);                                  \
        const float fg = sigm(af0 + af1 + xf);                                  \
        const float gg = tanh_f(ag0 + ag1 + xgp);                               \
        const float og = sigm(ao0 + ao1 + xo);                                  \
        c = fmaf(fg, c, ig * gg);                                               \
        const float hv_ = og * tanh_f(c);                                       \
        const __half hh = __float2half(hv_);                                    \
        ((u16*)&hbuf[WB][0])[hj] = (u16)__half_as_ushort(hh);                   \
        hout[(size_t)(T) * 128] = hh;            /* fire-and-forget */          \
        wg_barrier();                            /* h(T) visible */             \
    } while (0)

    for (int t = 0; t < 1024; t += 2) {
        STEP(t,     0, 1, xa, (t + 2 < 1024 ? t + 2 : 1023));
        STEP(t + 1, 1, 0, xb, (t + 3 < 1024 ? t + 3 : 1023));
    }
#undef STEP
}

// ---------------------------------------------------------------------------
// K3: y[m=131072][64] = h_seq(f16)[m][128] @ W1^T + b1   (f16 MFMA)
// ---------------------------------------------------------------------------
__global__ __launch_bounds__(256, 2)
void k3_gemm_out(const u16* __restrict__ hseq, const float* __restrict__ W1,
                 const float* __restrict__ b1, float* __restrict__ y) {
    const int m0 = blockIdx.x * 128;
    const int tid = threadIdx.x;
    const int wave = tid >> 6, lane = tid & 63;
    const int lanelo = lane & 15, quad = lane >> 4;

    __shared__ __align__(16) u16 Ah[128 * 136];
    __shared__ __align__(16) u16 Bw[64 * 136];
    __shared__ float b1s[64];

    {
        const int row = tid >> 1, cg = (tid & 1) * 64;
        const u16* src = hseq + (size_t)(m0 + row) * 128 + cg;
#pragma unroll
        for (int i = 0; i < 8; ++i)
            *(s16x8*)&Ah[row * 136 + cg + i * 8] = *(const s16x8*)(src + i * 8);
    }
    {
        const int row = tid >> 2, cg = (tid & 3) * 32;
        const float* src = W1 + (size_t)row * 128 + cg;
#pragma unroll
        for (int i = 0; i < 4; ++i) {
            float4 v0 = *(const float4*)(src + i * 8);
            float4 v1 = *(const float4*)(src + i * 8 + 4);
            *(s16x8*)&Bw[row * 136 + cg + i * 8] = pack_f16x8(v0, v1);
        }
    }
    if (tid < 64) b1s[tid] = b1[tid];
    __syncthreads();

    f16x8 af[2][4], bf[4][4];
#pragma unroll
    for (int mt = 0; mt < 2; ++mt)
#pragma unroll
        for (int kt = 0; kt < 4; ++kt)
            af[mt][kt] = __builtin_bit_cast(f16x8,
                *(const s16x8*)&Ah[(wave * 32 + mt * 16 + lanelo) * 136 + kt * 32 + quad * 8]);
#pragma unroll
    for (int nt = 0; nt < 4; ++nt)
#pragma unroll
        for (int kt = 0; kt < 4; ++kt)
            bf[nt][kt] = __builtin_bit_cast(f16x8,
                *(const s16x8*)&Bw[(nt * 16 + lanelo) * 136 + kt * 32 + quad * 8]);

    f32x4 acc[2][4];
#pragma unroll
    for (int mt = 0; mt < 2; ++mt)
#pragma unroll
        for (int nt = 0; nt < 4; ++nt) acc[mt][nt] = (f32x4)0.f;
#pragma unroll
    for (int kt = 0; kt < 4; ++kt)
#pragma unroll
        for (int mt = 0; mt < 2; ++mt)
#pragma unroll
            for (int nt = 0; nt < 4; ++nt)
                acc[mt][nt] = MFMA16H(af[mt][kt], bf[nt][kt], acc[mt][nt]);

#pragma unroll
    for (int mt = 0; mt < 2; ++mt)
#pragma unroll
        for (int nt = 0; nt < 4; ++nt) {
            const int n = nt * 16 + lanelo;
            const float bs = b1s[n];
            const int mr = m0 + wave * 32 + mt * 16 + quad * 4;
#pragma unroll
            for (int r = 0; r < 4; ++r)
                y[(size_t)(mr + r) * 64 + n] = acc[mt][nt][r] + bs;
        }
}

// ---------------------------------------------------------------------------
extern "C" void kernel_launch(void* const* d_in, const int* in_sizes, int n_in,
                              void* d_out, int out_size, void* d_ws, size_t ws_size,
                              hipStream_t stream) {
    const float* x    = (const float*)d_in[0];
    const float* W_ih = (const float*)d_in[1];
    const float* W_hh = (const float*)d_in[2];
    const float* b_ih = (const float*)d_in[3];
    const float* b_hh = (const float*)d_in[4];
    const float* W1   = (const float*)d_in[5];
    const float* b1   = (const float*)d_in[6];
    float* y = (float*)d_out;

    const size_t XG_BYTES = (size_t)131072 * 512 * 2;   // x_gates fp16: 134 MB
    const size_t HS_BYTES = (size_t)131072 * 128 * 2;   // h_seq  fp16:  33.5 MB
    if (ws_size < XG_BYTES + HS_BYTES) return;

    __half* xg   = (__half*)d_ws;
    __half* hseq = (__half*)((char*)d_ws + XG_BYTES);

    k1_gemm_xgates<<<dim3(4, 1024), 256, 0, stream>>>(x, W_ih, b_ih, b_hh, xg);
    k2_lstm_rec<<<128, 128, 0, stream>>>(xg, W_hh, hseq);
    k3_gemm_out<<<1024, 256, 0, stream>>>((const u16*)hseq, W1, b1, y);
}

// Round 4
// 909.124 us; speedup vs baseline: 1.8918x; 1.8918x over previous
//
#include <hip/hip_runtime.h>
#include <hip/hip_fp16.h>

typedef __attribute__((ext_vector_type(8))) short  s16x8;   // 8x16-bit (4 VGPRs)
typedef __attribute__((ext_vector_type(4))) float  f32x4;   // MFMA C/D frag
typedef __attribute__((ext_vector_type(4))) unsigned short u16x4;
typedef _Float16 f16x2 __attribute__((ext_vector_type(2)));
typedef _Float16 f16x8 __attribute__((ext_vector_type(8)));
typedef unsigned short u16;

#define MFMA16B(A, B, C) __builtin_amdgcn_mfma_f32_16x16x32_bf16((A), (B), (C), 0, 0, 0)
#define MFMA16H(A, B, C) __builtin_amdgcn_mfma_f32_16x16x32_f16((A), (B), (C), 0, 0, 0)

static __device__ __forceinline__ u16 f2bf(float f) {
    union { float f; unsigned u; } v; v.f = f;
    unsigned r = (v.u + 0x7fffu + ((v.u >> 16) & 1u)) >> 16;   // RNE
    return (u16)r;
}

static __device__ __forceinline__ s16x8 pack_f16x8(float4 a, float4 b) {
    s16x8 r;
    r[0] = (short)__half_as_ushort(__float2half_rn(a.x));
    r[1] = (short)__half_as_ushort(__float2half_rn(a.y));
    r[2] = (short)__half_as_ushort(__float2half_rn(a.z));
    r[3] = (short)__half_as_ushort(__float2half_rn(a.w));
    r[4] = (short)__half_as_ushort(__float2half_rn(b.x));
    r[5] = (short)__half_as_ushort(__float2half_rn(b.y));
    r[6] = (short)__half_as_ushort(__float2half_rn(b.z));
    r[7] = (short)__half_as_ushort(__float2half_rn(b.w));
    return r;
}

static __device__ __forceinline__ unsigned pk2f16(float a, float b) {
    unsigned lo = __half_as_ushort(__float2half_rn(a));
    unsigned hi = __half_as_ushort(__float2half_rn(b));
    return lo | (hi << 16);
}

static __device__ __forceinline__ float hu2f(u16 v) {
    __half_raw hr; hr.x = v; return __half2float(__half(hr));
}

// 2-way f16 dot with f32 accumulate: v_dot2_f32_f16.
static __device__ __forceinline__ float dot2(unsigned a, unsigned b, float c) {
#if __has_builtin(__builtin_amdgcn_fdot2)
    return __builtin_amdgcn_fdot2(__builtin_bit_cast(f16x2, a),
                                  __builtin_bit_cast(f16x2, b), c, false);
#else
    f16x2 av = __builtin_bit_cast(f16x2, a), bv = __builtin_bit_cast(f16x2, b);
    return fmaf((float)av[0], (float)bv[0], fmaf((float)av[1], (float)bv[1], c));
#endif
}

// fast sigmoid / tanh via v_exp + v_rcp (saturating, NaN-free at extremes)
static __device__ __forceinline__ float sigm(float x) {
    return __builtin_amdgcn_rcpf(1.f + __expf(-x));
}
static __device__ __forceinline__ float tanh_f(float x) {
    float e = __expf(-2.f * x);          // x->-inf: e=inf -> rcp=0 -> -1; x->+inf: e=0 -> +1
    return fmaf(2.f, __builtin_amdgcn_rcpf(1.f + e), -1.f);
}

// LDS-only workgroup barrier (no vmcnt drain -> global prefetch stays in flight).
static __device__ __forceinline__ void wg_barrier() {
    asm volatile("s_waitcnt lgkmcnt(0)\n\ts_barrier" ::: "memory");
}

// DPP quad-perm broadcast: every lane of each 4-lane quad gets lane (ctrl) of
// the quad. ctrl: 0x00=lane0, 0x55=lane1, 0xAA=lane2, 0xFF=lane3.
#define DPPB(v, ctrl) __builtin_bit_cast(float, __builtin_amdgcn_update_dpp(    \
        0, __builtin_bit_cast(int, (v)), (ctrl), 0xf, 0xf, true))

// ---------------------------------------------------------------------------
// K1: x_gates[m=131072][512] (fp16) = x[m][300] @ W_ih^T + (b_ih + b_hh)
// Output columns GATE-INTERLEAVED: column n' = col*4 + gate, i.e. xg[m][col][4]
// holds {i,f,g,o} preacts of h-column `col` contiguously (K2 reads 1 u16 per
// thread at t*512+tid). Implemented as a B-row permutation at staging time:
//   Bs row srow <- W_ih row grow(srow) = (srow&3)*128 + (n0>>2) + (srow>>2).
// grid (4, 1024): 4 n-blocks sharing an x-tile are dispatch-adjacent (L2 reuse).
// ---------------------------------------------------------------------------
__global__ __launch_bounds__(256, 2)
void k1_gemm_xgates(const float* __restrict__ x, const float* __restrict__ W_ih,
                    const float* __restrict__ b_ih, const float* __restrict__ b_hh,
                    __half* __restrict__ xg) {
    const int n0 = blockIdx.x * 128;       // 4 blocks
    const int m0 = blockIdx.y * 128;       // 1024 blocks
    const int tid = threadIdx.x;
    const int wave = tid >> 6, lane = tid & 63;
    const int lanelo = lane & 15, quad = lane >> 4;
    const int mw = (wave & 1) * 64, nw = (wave >> 1) * 64;

    __shared__ __align__(16) u16 As[128 * 40];
    __shared__ __align__(16) u16 Bs[128 * 40];

    f32x4 acc[4][4];
#pragma unroll
    for (int i = 0; i < 4; ++i)
#pragma unroll
        for (int j = 0; j < 4; ++j) acc[i][j] = (f32x4)0.f;

    const int srow = tid >> 1;
    const int scol = (tid & 1) * 16;
    // permuted gate-row for this staging row (n' = n0+srow -> W row)
    const int grow = (srow & 3) * 128 + (n0 >> 2) + (srow >> 2);

    for (int kc = 0; kc < 10; ++kc) {
        const int k0 = kc * 32;
        const float* srcA = x + (size_t)(m0 + srow) * 300 + k0 + scol;
        const float* srcB = W_ih + (size_t)grow * 300 + k0 + scol;
        if (kc < 9) {                       // full chunk, no bounds checks
#pragma unroll
            for (int i = 0; i < 4; ++i) {
                const int col = scol + i * 4;
                float4 v = *(const float4*)(srcA + i * 4);
                u16x4 w; w.x = f2bf(v.x); w.y = f2bf(v.y); w.z = f2bf(v.z); w.w = f2bf(v.w);
                *(u16x4*)&As[srow * 40 + col] = w;
                float4 u = *(const float4*)(srcB + i * 4);
                u16x4 q; q.x = f2bf(u.x); q.y = f2bf(u.y); q.z = f2bf(u.z); q.w = f2bf(u.w);
                *(u16x4*)&Bs[srow * 40 + col] = q;
            }
        } else {                            // tail chunk (K 288..299, rest zero)
#pragma unroll
            for (int i = 0; i < 4; ++i) {
                const int col = scol + i * 4;
                float4 v = {0.f, 0.f, 0.f, 0.f}, u = {0.f, 0.f, 0.f, 0.f};
                if (k0 + col + 3 < 300) { v = *(const float4*)(srcA + i * 4);
                                          u = *(const float4*)(srcB + i * 4); }
                u16x4 w; w.x = f2bf(v.x); w.y = f2bf(v.y); w.z = f2bf(v.z); w.w = f2bf(v.w);
                *(u16x4*)&As[srow * 40 + col] = w;
                u16x4 q; q.x = f2bf(u.x); q.y = f2bf(u.y); q.z = f2bf(u.z); q.w = f2bf(u.w);
                *(u16x4*)&Bs[srow * 40 + col] = q;
            }
        }
        __syncthreads();

        s16x8 af[4], bf[4];
#pragma unroll
        for (int mt = 0; mt < 4; ++mt)
            af[mt] = *(const s16x8*)&As[(mw + mt * 16 + lanelo) * 40 + quad * 8];
#pragma unroll
        for (int nt = 0; nt < 4; ++nt)
            bf[nt] = *(const s16x8*)&Bs[(nw + nt * 16 + lanelo) * 40 + quad * 8];
#pragma unroll
        for (int mt = 0; mt < 4; ++mt)
#pragma unroll
            for (int nt = 0; nt < 4; ++nt)
                acc[mt][nt] = MFMA16B(af[mt], bf[nt], acc[mt][nt]);
        __syncthreads();
    }

#pragma unroll
    for (int nt = 0; nt < 4; ++nt) {
        const int n = n0 + nw + nt * 16 + lanelo;      // permuted output column
        const int g = (n & 3) * 128 + (n >> 2);        // original gate row
        const float bs = b_ih[g] + b_hh[g];
#pragma unroll
        for (int mt = 0; mt < 4; ++mt) {
            const int mr = m0 + mw + mt * 16 + quad * 4;
#pragma unroll
            for (int r = 0; r < 4; ++r)
                xg[(size_t)(mr + r) * 512 + n] = __float2half(acc[mt][nt][r] + bs);
        }
    }
}

// ---------------------------------------------------------------------------
// K2 v7: LSTM recurrence, 512 threads (8 waves, 2/SIMD), 1 gate row/thread.
//   128 WGs (one batch row each). tid = col*4 + g: the 4 gate rows of column
//   `col` sit in one quad. Each thread: W_hh row g*128+col stationary as 64
//   packed-f16 dwords (64 VGPR -> total ~100 VGPR -> 2 waves/SIMD latency
//   hiding, the lever v5/v6 lacked). Per step: 16 b128 broadcast h-reads,
//   64 dot2 in 4 chains, own-gate activation (1 exp+1 rcp, branchless
//   sigm/tanh), 4 DPP quad broadcasts of activated gates, redundant in-quad
//   cell update, predicated h writes (g0: LDS, g1: global), 1 barrier.
//   xg = 1 coalesced u16/thread/step, 2-step register prefetch, never drained.
// ---------------------------------------------------------------------------
__global__ __launch_bounds__(512, 2)
void k2_lstm_rec(const __half* __restrict__ xg_all, const float* __restrict__ W_hh,
                 __half* __restrict__ h_seq) {
    const int b = blockIdx.x;             // batch row 0..127
    const int tid = threadIdx.x;          // 0..511
    const int col = tid >> 2;             // h column 0..127
    const int g = tid & 3;                // 0=i, 1=f, 2=g, 3=o

    __shared__ __align__(16) unsigned hbuf[2][64];    // ping-pong h (f16 packed)

    // --- stationary W_hh row g*128+col (f32 -> packed f16 pairs, 64 VGPRs)
    unsigned wr[64];
    {
        const float2* rp = (const float2*)(W_hh + (size_t)(g * 128 + col) * 128);
#pragma unroll
        for (int k = 0; k < 64; ++k) { float2 a = rp[k]; wr[k] = pk2f16(a.x, a.y); }
    }

    // branchless activation: act = sb*sigm(sb*x)+bb  (g==2 -> tanh, else sigmoid)
    const float sb = (g == 2) ? 2.f : 1.f;
    const float bb = (g == 2) ? -1.f : 0.f;

    // xg: [t][col][4] u16 -> element index t*512 + tid (coalesced)
    const u16* xp = (const u16*)xg_all + (size_t)b * 1024 * 512 + tid;
    u16 xa = xp[0];                        // t=0 preact (my gate)
    u16 xb = xp[512];                      // t=1

    if (tid < 64) hbuf[0][tid] = 0u;       // h(-1) = 0
    float c = 0.f;                         // cell state (redundant per quad)
    __half* hout = h_seq + (size_t)b * 1024 * 128 + col;
    __syncthreads();

#define STEP(T, RB, WB, XR, NXT) do {                                           \
        const uint4* _hp = (const uint4*)&hbuf[RB][0];                          \
        float _s0 = 0.f, _s1 = 0.f, _s2 = 0.f, _s3 = 0.f;                       \
        _Pragma("unroll")                                                       \
        for (int _j = 0; _j < 16; ++_j) {                                       \
            const uint4 _hv = _hp[_j];                                          \
            const int _k = _j * 4;                                              \
            _s0 = dot2(wr[_k + 0], _hv.x, _s0);                                 \
            _s1 = dot2(wr[_k + 1], _hv.y, _s1);                                 \
            _s2 = dot2(wr[_k + 2], _hv.z, _s2);                                 \
            _s3 = dot2(wr[_k + 3], _hv.w, _s3);                                 \
        }                                                                       \
        const float _pre = (_s0 + _s1) + (_s2 + _s3) + hu2f(XR);                \
        XR = xp[(size_t)(NXT) * 512];            /* prefetch 2 ahead */         \
        const float _act = fmaf(sb, sigm(sb * _pre), bb);                       \
        const float _ig = DPPB(_act, 0x00);      /* lane g=0: i */              \
        const float _fg = DPPB(_act, 0x55);      /* lane g=1: f */              \
        const float _gg = DPPB(_act, 0xAA);      /* lane g=2: g */              \
        const float _og = DPPB(_act, 0xFF);      /* lane g=3: o */              \
        c = fmaf(_fg, c, _ig * _gg);                                            \
        const float _hv_ = _og * tanh_f(c);                                     \
        const __half _hh = __float2half(_hv_);                                  \
        if (g == 0) ((u16*)&hbuf[WB][0])[col] = (u16)__half_as_ushort(_hh);     \
        if (g == 1) hout[(size_t)(T) * 128] = _hh;   /* fire-and-forget */      \
        wg_barrier();                            /* h(T) visible */             \
    } while (0)

    for (int t = 0; t < 1024; t += 2) {
        STEP(t,     0, 1, xa, (t + 2 < 1024 ? t + 2 : 1023));
        STEP(t + 1, 1, 0, xb, (t + 3 < 1024 ? t + 3 : 1023));
    }
#undef STEP
}

// ---------------------------------------------------------------------------
// K3: y[m=131072][64] = h_seq(f16)[m][128] @ W1^T + b1   (f16 MFMA)
// ---------------------------------------------------------------------------
__global__ __launch_bounds__(256, 2)
void k3_gemm_out(const u16* __restrict__ hseq, const float* __restrict__ W1,
                 const float* __restrict__ b1, float* __restrict__ y) {
    const int m0 = blockIdx.x * 128;
    const int tid = threadIdx.x;
    const int wave = tid >> 6, lane = tid & 63;
    const int lanelo = lane & 15, quad = lane >> 4;

    __shared__ __align__(16) u16 Ah[128 * 136];
    __shared__ __align__(16) u16 Bw[64 * 136];
    __shared__ float b1s[64];

    {
        const int row = tid >> 1, cg = (tid & 1) * 64;
        const u16* src = hseq + (size_t)(m0 + row) * 128 + cg;
#pragma unroll
        for (int i = 0; i < 8; ++i)
            *(s16x8*)&Ah[row * 136 + cg + i * 8] = *(const s16x8*)(src + i * 8);
    }
    {
        const int row = tid >> 2, cg = (tid & 3) * 32;
        const float* src = W1 + (size_t)row * 128 + cg;
#pragma unroll
        for (int i = 0; i < 4; ++i) {
            float4 v0 = *(const float4*)(src + i * 8);
            float4 v1 = *(const float4*)(src + i * 8 + 4);
            *(s16x8*)&Bw[row * 136 + cg + i * 8] = pack_f16x8(v0, v1);
        }
    }
    if (tid < 64) b1s[tid] = b1[tid];
    __syncthreads();

    f16x8 af[2][4], bf[4][4];
#pragma unroll
    for (int mt = 0; mt < 2; ++mt)
#pragma unroll
        for (int kt = 0; kt < 4; ++kt)
            af[mt][kt] = __builtin_bit_cast(f16x8,
                *(const s16x8*)&Ah[(wave * 32 + mt * 16 + lanelo) * 136 + kt * 32 + quad * 8]);
#pragma unroll
    for (int nt = 0; nt < 4; ++nt)
#pragma unroll
        for (int kt = 0; kt < 4; ++kt)
            bf[nt][kt] = __builtin_bit_cast(f16x8,
                *(const s16x8*)&Bw[(nt * 16 + lanelo) * 136 + kt * 32 + quad * 8]);

    f32x4 acc[2][4];
#pragma unroll
    for (int mt = 0; mt < 2; ++mt)
#pragma unroll
        for (int nt = 0; nt < 4; ++nt) acc[mt][nt] = (f32x4)0.f;
#pragma unroll
    for (int kt = 0; kt < 4; ++kt)
#pragma unroll
        for (int mt = 0; mt < 2; ++mt)
#pragma unroll
            for (int nt = 0; nt < 4; ++nt)
                acc[mt][nt] = MFMA16H(af[mt][kt], bf[nt][kt], acc[mt][nt]);

#pragma unroll
    for (int mt = 0; mt < 2; ++mt)
#pragma unroll
        for (int nt = 0; nt < 4; ++nt) {
            const int n = nt * 16 + lanelo;
            const float bs = b1s[n];
            const int mr = m0 + wave * 32 + mt * 16 + quad * 4;
#pragma unroll
            for (int r = 0; r < 4; ++r)
                y[(size_t)(mr + r) * 64 + n] = acc[mt][nt][r] + bs;
        }
}

// ---------------------------------------------------------------------------
extern "C" void kernel_launch(void* const* d_in, const int* in_sizes, int n_in,
                              void* d_out, int out_size, void* d_ws, size_t ws_size,
                              hipStream_t stream) {
    const float* x    = (const float*)d_in[0];
    const float* W_ih = (const float*)d_in[1];
    const float* W_hh = (const float*)d_in[2];
    const float* b_ih = (const float*)d_in[3];
    const float* b_hh = (const float*)d_in[4];
    const float* W1   = (const float*)d_in[5];
    const float* b1   = (const float*)d_in[6];
    float* y = (float*)d_out;

    const size_t XG_BYTES = (size_t)131072 * 512 * 2;   // x_gates fp16: 134 MB
    const size_t HS_BYTES = (size_t)131072 * 128 * 2;   // h_seq  fp16:  33.5 MB
    if (ws_size < XG_BYTES + HS_BYTES) return;

    __half* xg   = (__half*)d_ws;
    __half* hseq = (__half*)((char*)d_ws + XG_BYTES);

    k1_gemm_xgates<<<dim3(4, 1024), 256, 0, stream>>>(x, W_ih, b_ih, b_hh, xg);
    k2_lstm_rec<<<128, 512, 0, stream>>>(xg, W_hh, hseq);
    k3_gemm_out<<<1024, 256, 0, stream>>>((const u16*)hseq, W1, b1, y);
}

// Round 5
// 884.935 us; speedup vs baseline: 1.9435x; 1.0273x over previous
//
#include <hip/hip_runtime.h>
#include <hip/hip_fp16.h>

typedef __attribute__((ext_vector_type(8))) short  s16x8;   // 8x16-bit (4 VGPRs)
typedef __attribute__((ext_vector_type(4))) float  f32x4;   // MFMA C/D frag
typedef __attribute__((ext_vector_type(4))) unsigned short u16x4;
typedef _Float16 f16x2 __attribute__((ext_vector_type(2)));
typedef _Float16 f16x8 __attribute__((ext_vector_type(8)));
typedef unsigned short u16;

#define MFMA16B(A, B, C) __builtin_amdgcn_mfma_f32_16x16x32_bf16((A), (B), (C), 0, 0, 0)
#define MFMA16H(A, B, C) __builtin_amdgcn_mfma_f32_16x16x32_f16((A), (B), (C), 0, 0, 0)

static __device__ __forceinline__ u16 f2bf(float f) {
    union { float f; unsigned u; } v; v.f = f;
    unsigned r = (v.u + 0x7fffu + ((v.u >> 16) & 1u)) >> 16;   // RNE
    return (u16)r;
}

static __device__ __forceinline__ s16x8 pack_f16x8(float4 a, float4 b) {
    s16x8 r;
    r[0] = (short)__half_as_ushort(__float2half_rn(a.x));
    r[1] = (short)__half_as_ushort(__float2half_rn(a.y));
    r[2] = (short)__half_as_ushort(__float2half_rn(a.z));
    r[3] = (short)__half_as_ushort(__float2half_rn(a.w));
    r[4] = (short)__half_as_ushort(__float2half_rn(b.x));
    r[5] = (short)__half_as_ushort(__float2half_rn(b.y));
    r[6] = (short)__half_as_ushort(__float2half_rn(b.z));
    r[7] = (short)__half_as_ushort(__float2half_rn(b.w));
    return r;
}

static __device__ __forceinline__ float hu2f(u16 v) {
    __half_raw hr; hr.x = v; return __half2float(__half(hr));
}

// fast sigmoid / tanh via v_exp + v_rcp (saturating, NaN-free at extremes)
static __device__ __forceinline__ float sigm(float x) {
    return __builtin_amdgcn_rcpf(1.f + __expf(-x));
}
static __device__ __forceinline__ float tanh_f(float x) {
    float e = __expf(-2.f * x);          // x->-inf: e=inf -> rcp=0 -> -1; x->+inf: e=0 -> +1
    return fmaf(2.f, __builtin_amdgcn_rcpf(1.f + e), -1.f);
}

// LDS-only workgroup barrier (no vmcnt drain -> global prefetch stays in flight).
static __device__ __forceinline__ void wg_barrier() {
    asm volatile("s_waitcnt lgkmcnt(0)\n\ts_barrier" ::: "memory");
}

// same-wave LDS write->read ordering fence (gather spread, no barrier needed)
static __device__ __forceinline__ void lds_fence() {
    asm volatile("s_waitcnt lgkmcnt(0)" ::: "memory");
}

// DPP quad-perm broadcast: every lane of each 4-lane quad gets lane (ctrl) of
// the quad. ctrl: 0x00=lane0, 0x55=lane1, 0xAA=lane2, 0xFF=lane3.
#define DPPB(v, ctrl) __builtin_bit_cast(float, __builtin_amdgcn_update_dpp(    \
        0, __builtin_bit_cast(int, (v)), (ctrl), 0xf, 0xf, true))

// ---------------------------------------------------------------------------
// K1: x_gates[m=131072][512] (fp16) = x[m][300] @ W_ih^T + (b_ih + b_hh)
// Output columns GATE-INTERLEAVED: column n' = col*4 + gate (xg[m][col][4]).
// Implemented as a B-row permutation at staging time:
//   Bs row srow <- W_ih row grow(srow) = (srow&3)*128 + (n0>>2) + (srow>>2).
// grid (4, 1024): 4 n-blocks sharing an x-tile are dispatch-adjacent (L2 reuse).
// ---------------------------------------------------------------------------
__global__ __launch_bounds__(256, 2)
void k1_gemm_xgates(const float* __restrict__ x, const float* __restrict__ W_ih,
                    const float* __restrict__ b_ih, const float* __restrict__ b_hh,
                    __half* __restrict__ xg) {
    const int n0 = blockIdx.x * 128;       // 4 blocks
    const int m0 = blockIdx.y * 128;       // 1024 blocks
    const int tid = threadIdx.x;
    const int wave = tid >> 6, lane = tid & 63;
    const int lanelo = lane & 15, quad = lane >> 4;
    const int mw = (wave & 1) * 64, nw = (wave >> 1) * 64;

    __shared__ __align__(16) u16 As[128 * 40];
    __shared__ __align__(16) u16 Bs[128 * 40];

    f32x4 acc[4][4];
#pragma unroll
    for (int i = 0; i < 4; ++i)
#pragma unroll
        for (int j = 0; j < 4; ++j) acc[i][j] = (f32x4)0.f;

    const int srow = tid >> 1;
    const int scol = (tid & 1) * 16;
    // permuted gate-row for this staging row (n' = n0+srow -> W row)
    const int grow = (srow & 3) * 128 + (n0 >> 2) + (srow >> 2);

    for (int kc = 0; kc < 10; ++kc) {
        const int k0 = kc * 32;
        const float* srcA = x + (size_t)(m0 + srow) * 300 + k0 + scol;
        const float* srcB = W_ih + (size_t)grow * 300 + k0 + scol;
        if (kc < 9) {                       // full chunk, no bounds checks
#pragma unroll
            for (int i = 0; i < 4; ++i) {
                const int col = scol + i * 4;
                float4 v = *(const float4*)(srcA + i * 4);
                u16x4 w; w.x = f2bf(v.x); w.y = f2bf(v.y); w.z = f2bf(v.z); w.w = f2bf(v.w);
                *(u16x4*)&As[srow * 40 + col] = w;
                float4 u = *(const float4*)(srcB + i * 4);
                u16x4 q; q.x = f2bf(u.x); q.y = f2bf(u.y); q.z = f2bf(u.z); q.w = f2bf(u.w);
                *(u16x4*)&Bs[srow * 40 + col] = q;
            }
        } else {                            // tail chunk (K 288..299, rest zero)
#pragma unroll
            for (int i = 0; i < 4; ++i) {
                const int col = scol + i * 4;
                float4 v = {0.f, 0.f, 0.f, 0.f}, u = {0.f, 0.f, 0.f, 0.f};
                if (k0 + col + 3 < 300) { v = *(const float4*)(srcA + i * 4);
                                          u = *(const float4*)(srcB + i * 4); }
                u16x4 w; w.x = f2bf(v.x); w.y = f2bf(v.y); w.z = f2bf(v.z); w.w = f2bf(v.w);
                *(u16x4*)&As[srow * 40 + col] = w;
                u16x4 q; q.x = f2bf(u.x); q.y = f2bf(u.y); q.z = f2bf(u.z); q.w = f2bf(u.w);
                *(u16x4*)&Bs[srow * 40 + col] = q;
            }
        }
        __syncthreads();

        s16x8 af[4], bf[4];
#pragma unroll
        for (int mt = 0; mt < 4; ++mt)
            af[mt] = *(const s16x8*)&As[(mw + mt * 16 + lanelo) * 40 + quad * 8];
#pragma unroll
        for (int nt = 0; nt < 4; ++nt)
            bf[nt] = *(const s16x8*)&Bs[(nw + nt * 16 + lanelo) * 40 + quad * 8];
#pragma unroll
        for (int mt = 0; mt < 4; ++mt)
#pragma unroll
            for (int nt = 0; nt < 4; ++nt)
                acc[mt][nt] = MFMA16B(af[mt], bf[nt], acc[mt][nt]);
        __syncthreads();
    }

#pragma unroll
    for (int nt = 0; nt < 4; ++nt) {
        const int n = n0 + nw + nt * 16 + lanelo;      // permuted output column
        const int g = (n & 3) * 128 + (n >> 2);        // original gate row
        const float bs = b_ih[g] + b_hh[g];
#pragma unroll
        for (int mt = 0; mt < 4; ++mt) {
            const int mr = m0 + mw + mt * 16 + quad * 4;
#pragma unroll
            for (int r = 0; r < 4; ++r)
                xg[(size_t)(mr + r) * 512 + n] = __float2half(acc[mt][nt][r] + bs);
        }
    }
}

// ---------------------------------------------------------------------------
// K2 v8: LSTM recurrence with MFMA GEMV (matrix pipe does the dot work).
//   128 WGs (one batch row) x 512 threads (8 waves, 2/SIMD).
//   Per step: gates[512] = h[1x128] @ W_hh_perm^T via mfma_f32_16x16x32_f16,
//   M=16 with 1 real row (rows 1-15 unused -> no cross-row contamination).
//   Wave w owns gate cols [64w, 64w+64): 4 N-tiles x 4 K-steps B-frags
//   stationary in VGPRs (64 VGPR, f16 - same numerics as v7's dot2).
//   A-frag: lanes l&15==0 read h (ds_read_b128 from LDS); others read a zero
//   block (cndmask'd base, hoisted). Row-0 results sit in lanes 0-15 reg 0:
//   4 masked ds_write_b32 + same-wave lgkmcnt(0) + 1 ds_read_b32 spread one
//   gate to each lane -> v7's proven act / DPP-quad / cell path unchanged.
//   h double-buffered in LDS, ONE barrier per step. xg: 1 coalesced u16 per
//   thread per step, 2-step register prefetch, never drained at barriers.
// ---------------------------------------------------------------------------
__global__ __launch_bounds__(512, 2)
void k2_lstm_rec(const __half* __restrict__ xg_all, const float* __restrict__ W_hh,
                 __half* __restrict__ h_seq) {
    const int b = blockIdx.x;             // batch row 0..127
    const int tid = threadIdx.x;          // 0..511
    const int w = tid >> 6;               // wave 0..7 -> gate cols [64w, 64w+64)
    const int l = tid & 63;               // lane
    const int col = 16 * w + (l >> 2);    // owned h column 0..127
    const int g = l & 3;                  // 0=i, 1=f, 2=g, 3=o
    const bool row0 = (l & 15) == 0;      // lanes supplying the real A row

    __shared__ __align__(16) u16  hbuf[2][128];   // ping-pong h (f16)
    __shared__ __align__(16) u16  zblk[104];      // zero block for A rows 1..15
    __shared__ __align__(16) float gate_lds[512]; // per-wave gate spread region

    // --- stationary W_hh B-frags (gate-permuted cols, f32 -> f16), 64 VGPRs
    // B-frag for tile t, k-step ks: lane l holds W_perm[n=64w+16t+(l&15)]
    //   [k = 32ks + (l>>4)*8 .. +8]  (same layout K1/K3 use, verified working)
    f16x8 bfrag[4][4];
#pragma unroll
    for (int t = 0; t < 4; ++t)
#pragma unroll
        for (int ks = 0; ks < 4; ++ks) {
            const int n = 64 * w + 16 * t + (l & 15);
            const int grow = (n & 3) * 128 + (n >> 2);    // gate-perm -> W row
            const float* p = W_hh + (size_t)grow * 128 + 32 * ks + (l >> 4) * 8;
            float4 v0 = *(const float4*)p;
            float4 v1 = *(const float4*)(p + 4);
            bfrag[t][ks] = __builtin_bit_cast(f16x8, pack_f16x8(v0, v1));
        }

    // branchless activation: act = sb*sigm(sb*x)+bb  (g==2 -> tanh, else sigmoid)
    const float sb = (g == 2) ? 2.f : 1.f;
    const float bb = (g == 2) ? -1.f : 0.f;

    // xg: [t][col][4] u16 -> element index t*512 + tid (coalesced)
    const u16* xp = (const u16*)xg_all + (size_t)b * 1024 * 512 + tid;
    u16 xa = xp[0];                        // t=0 preact (my gate)
    u16 xb = xp[512];                      // t=1

    if (tid < 128) hbuf[0][tid] = 0;       // h(-1) = 0
    if (tid < 104) zblk[tid] = 0;          // zero A rows (covers reads +0..+192B)

    // hoisted A-frag base addresses (per ping-pong buffer)
    const u16* aA0 = row0 ? &hbuf[0][(l >> 4) * 8] : &zblk[0];
    const u16* aA1 = row0 ? &hbuf[1][(l >> 4) * 8] : &zblk[0];
    float* gw = &gate_lds[64 * w + l];     // gather write base (lanes 0..15)
    const float* gr = &gate_lds[64 * w + l];  // spread read (all lanes)

    float c = 0.f;                         // cell state (redundant per quad)
    __half* hout = h_seq + (size_t)b * 1024 * 128 + col;
    __syncthreads();

#define STEP(T, APTR, WB, XR, NXT) do {                                         \
        s16x8 _a0 = *(const s16x8*)(APTR);                                      \
        s16x8 _a1 = *(const s16x8*)(APTR + 32);                                 \
        s16x8 _a2 = *(const s16x8*)(APTR + 64);                                 \
        s16x8 _a3 = *(const s16x8*)(APTR + 96);                                 \
        f32x4 _ac0 = (f32x4)0.f, _ac1 = (f32x4)0.f;                             \
        f32x4 _ac2 = (f32x4)0.f, _ac3 = (f32x4)0.f;                             \
        f16x8 _af;                                                              \
        _af = __builtin_bit_cast(f16x8, _a0);                                   \
        _ac0 = MFMA16H(_af, bfrag[0][0], _ac0);                                 \
        _ac1 = MFMA16H(_af, bfrag[1][0], _ac1);                                 \
        _ac2 = MFMA16H(_af, bfrag[2][0], _ac2);                                 \
        _ac3 = MFMA16H(_af, bfrag[3][0], _ac3);                                 \
        _af = __builtin_bit_cast(f16x8, _a1);                                   \
        _ac0 = MFMA16H(_af, bfrag[0][1], _ac0);                                 \
        _ac1 = MFMA16H(_af, bfrag[1][1], _ac1);                                 \
        _ac2 = MFMA16H(_af, bfrag[2][1], _ac2);                                 \
        _ac3 = MFMA16H(_af, bfrag[3][1], _ac3);                                 \
        _af = __builtin_bit_cast(f16x8, _a2);                                   \
        _ac0 = MFMA16H(_af, bfrag[0][2], _ac0);                                 \
        _ac1 = MFMA16H(_af, bfrag[1][2], _ac1);                                 \
        _ac2 = MFMA16H(_af, bfrag[2][2], _ac2);                                 \
        _ac3 = MFMA16H(_af, bfrag[3][2], _ac3);                                 \
        _af = __builtin_bit_cast(f16x8, _a3);                                   \
        _ac0 = MFMA16H(_af, bfrag[0][3], _ac0);                                 \
        _ac1 = MFMA16H(_af, bfrag[1][3], _ac1);                                 \
        _ac2 = MFMA16H(_af, bfrag[2][3], _ac2);                                 \
        _ac3 = MFMA16H(_af, bfrag[3][3], _ac3);                                 \
        if (l < 16) {          /* row-0 gates: lanes 0-15, reg 0 of each tile */ \
            gw[0]  = _ac0[0];                                                   \
            gw[16] = _ac1[0];                                                   \
            gw[32] = _ac2[0];                                                   \
            gw[48] = _ac3[0];                                                   \
        }                                                                       \
        lds_fence();           /* same-wave write->read ordering */             \
        const float _pre = *gr + hu2f(XR);                                      \
        XR = xp[(size_t)(NXT) * 512];            /* prefetch 2 ahead */         \
        const float _act = fmaf(sb, sigm(sb * _pre), bb);                       \
        const float _ig = DPPB(_act, 0x00);      /* lane g=0: i */              \
        const float _fg = DPPB(_act, 0x55);      /* lane g=1: f */              \
        const float _gg = DPPB(_act, 0xAA);      /* lane g=2: g */              \
        const float _og = DPPB(_act, 0xFF);      /* lane g=3: o */              \
        c = fmaf(_fg, c, _ig * _gg);                                            \
        const float _hv = _og * tanh_f(c);                                      \
        const __half _hh = __float2half(_hv);                                   \
        if (g == 0) hbuf[WB][col] = (u16)__half_as_ushort(_hh);                 \
        if (g == 1) hout[(size_t)(T) * 128] = _hh;   /* fire-and-forget */      \
        wg_barrier();                            /* h(T) visible */             \
    } while (0)

    for (int t = 0; t < 1024; t += 2) {
        STEP(t,     aA0, 1, xa, (t + 2 < 1024 ? t + 2 : 1023));
        STEP(t + 1, aA1, 0, xb, (t + 3 < 1024 ? t + 3 : 1023));
    }
#undef STEP
}

// ---------------------------------------------------------------------------
// K3: y[m=131072][64] = h_seq(f16)[m][128] @ W1^T + b1   (f16 MFMA)
// ---------------------------------------------------------------------------
__global__ __launch_bounds__(256, 2)
void k3_gemm_out(const u16* __restrict__ hseq, const float* __restrict__ W1,
                 const float* __restrict__ b1, float* __restrict__ y) {
    const int m0 = blockIdx.x * 128;
    const int tid = threadIdx.x;
    const int wave = tid >> 6, lane = tid & 63;
    const int lanelo = lane & 15, quad = lane >> 4;

    __shared__ __align__(16) u16 Ah[128 * 136];
    __shared__ __align__(16) u16 Bw[64 * 136];
    __shared__ float b1s[64];

    {
        const int row = tid >> 1, cg = (tid & 1) * 64;
        const u16* src = hseq + (size_t)(m0 + row) * 128 + cg;
#pragma unroll
        for (int i = 0; i < 8; ++i)
            *(s16x8*)&Ah[row * 136 + cg + i * 8] = *(const s16x8*)(src + i * 8);
    }
    {
        const int row = tid >> 2, cg = (tid & 3) * 32;
        const float* src = W1 + (size_t)row * 128 + cg;
#pragma unroll
        for (int i = 0; i < 4; ++i) {
            float4 v0 = *(const float4*)(src + i * 8);
            float4 v1 = *(const float4*)(src + i * 8 + 4);
            *(s16x8*)&Bw[row * 136 + cg + i * 8] = pack_f16x8(v0, v1);
        }
    }
    if (tid < 64) b1s[tid] = b1[tid];
    __syncthreads();

    f16x8 af[2][4], bf[4][4];
#pragma unroll
    for (int mt = 0; mt < 2; ++mt)
#pragma unroll
        for (int kt = 0; kt < 4; ++kt)
            af[mt][kt] = __builtin_bit_cast(f16x8,
                *(const s16x8*)&Ah[(wave * 32 + mt * 16 + lanelo) * 136 + kt * 32 + quad * 8]);
#pragma unroll
    for (int nt = 0; nt < 4; ++nt)
#pragma unroll
        for (int kt = 0; kt < 4; ++kt)
            bf[nt][kt] = __builtin_bit_cast(f16x8,
                *(const s16x8*)&Bw[(nt * 16 + lanelo) * 136 + kt * 32 + quad * 8]);

    f32x4 acc[2][4];
#pragma unroll
    for (int mt = 0; mt < 2; ++mt)
#pragma unroll
        for (int nt = 0; nt < 4; ++nt) acc[mt][nt] = (f32x4)0.f;
#pragma unroll
    for (int kt = 0; kt < 4; ++kt)
#pragma unroll
        for (int mt = 0; mt < 2; ++mt)
#pragma unroll
            for (int nt = 0; nt < 4; ++nt)
                acc[mt][nt] = MFMA16H(af[mt][kt], bf[nt][kt], acc[mt][nt]);

#pragma unroll
    for (int mt = 0; mt < 2; ++mt)
#pragma unroll
        for (int nt = 0; nt < 4; ++nt) {
            const int n = nt * 16 + lanelo;
            const float bs = b1s[n];
            const int mr = m0 + wave * 32 + mt * 16 + quad * 4;
#pragma unroll
            for (int r = 0; r < 4; ++r)
                y[(size_t)(mr + r) * 64 + n] = acc[mt][nt][r] + bs;
        }
}

// ---------------------------------------------------------------------------
extern "C" void kernel_launch(void* const* d_in, const int* in_sizes, int n_in,
                              void* d_out, int out_size, void* d_ws, size_t ws_size,
                              hipStream_t stream) {
    const float* x    = (const float*)d_in[0];
    const float* W_ih = (const float*)d_in[1];
    const float* W_hh = (const float*)d_in[2];
    const float* b_ih = (const float*)d_in[3];
    const float* b_hh = (const float*)d_in[4];
    const float* W1   = (const float*)d_in[5];
    const float* b1   = (const float*)d_in[6];
    float* y = (float*)d_out;

    const size_t XG_BYTES = (size_t)131072 * 512 * 2;   // x_gates fp16: 134 MB
    const size_t HS_BYTES = (size_t)131072 * 128 * 2;   // h_seq  fp16:  33.5 MB
    if (ws_size < XG_BYTES + HS_BYTES) return;

    __half* xg   = (__half*)d_ws;
    __half* hseq = (__half*)((char*)d_ws + XG_BYTES);

    k1_gemm_xgates<<<dim3(4, 1024), 256, 0, stream>>>(x, W_ih, b_ih, b_hh, xg);
    k2_lstm_rec<<<128, 512, 0, stream>>>(xg, W_hh, hseq);
    k3_gemm_out<<<1024, 256, 0, stream>>>((const u16*)hseq, W1, b1, y);
}